// Round 1
// baseline (20613.405 us; speedup 1.0000x reference)
//
#include <hip/hip_runtime.h>
#include <math.h>

// Problem constants (from setup_inputs): B=256, T=256, D=80, H=512, 4H=2048, K=512
#define BB 256
#define TT 256
#define DDIM 80
#define HDIM 512
#define NGATE 2048
#define ROWSTRIDE 20480   // T*D

__device__ __forceinline__ float sigmoidf_(float v) { return 1.0f / (1.0f + expf(-v)); }

// ---------------- zero init (h0, c_enc, c_dec are contiguous at ws[0..393216)) ----
__global__ __launch_bounds__(256) void zero_kernel(float4* __restrict__ p, int n4) {
  int i = blockIdx.x * 256 + threadIdx.x;
  if (i < n4) p[i] = make_float4(0.f, 0.f, 0.f, 0.f);
}

// ---------------- bias sums (+ folded decoder bias) ------------------------------
__global__ __launch_bounds__(256) void bias_init_kernel(
    const float* __restrict__ eb1, const float* __restrict__ eb2,
    const float* __restrict__ db1, const float* __restrict__ db2,
    const float* __restrict__ dWih, const float* __restrict__ fcb,
    float* __restrict__ b_enc, float* __restrict__ b_dec0,
    float* __restrict__ b_eff, int do_eff) {
  int n = blockIdx.x * 256 + threadIdx.x;
  b_enc[n] = eb1[n] + eb2[n];
  float bd = db1[n] + db2[n];
  b_dec0[n] = bd;
  if (do_eff) {
    float acc = bd;
    #pragma unroll 16
    for (int d = 0; d < DDIM; d++) acc += dWih[n * DDIM + d] * fcb[d];
    b_eff[n] = acc;
  }
}

// ---------------- W_eff = dec_W_hh + dec_W_ih @ fc_W  (2048x512, K=80) ------------
__global__ __launch_bounds__(256) void fold_kernel(
    const float* __restrict__ dWih, const float* __restrict__ dWhh,
    const float* __restrict__ fcW, float* __restrict__ W_eff) {
  int n = blockIdx.x;
  int tid = threadIdx.x;
  __shared__ float sw[DDIM];
  if (tid < DDIM) sw[tid] = dWih[n * DDIM + tid];
  __syncthreads();
  for (int k = tid; k < HDIM; k += 256) {
    float acc = dWhh[n * HDIM + k];
    #pragma unroll 16
    for (int d = 0; d < DDIM; d++) acc += sw[d] * fcW[d * HDIM + k];
    W_eff[n * HDIM + k] = acc;
  }
}

// ---------------- fused LSTM step ------------------------------------------------
// grid = 512 blocks (16 row-tiles x 32 j-tiles), 256 threads.
// Block: rows [rt*16,+16), j-dims [jt*16,+16), all 4 gates; c updated in place,
// h ping-pongs. Optional x-part (K=80) and optional fused y_{t-1} output
// (decoder: y from the staged h_in rows).
__global__ __launch_bounds__(256) void lstm_step_kernel(
    const float* __restrict__ x,    // may be null; x[b*20480 + d]
    const float* __restrict__ Wih,  // [2048][80]   (used only if x)
    const float* __restrict__ Whh,  // [2048][512]
    const float* __restrict__ bias, // [2048]
    const float* __restrict__ h_in, // [256][512]
    float* __restrict__ c,          // [256][512] in-place
    float* __restrict__ h_out,      // [256][512]
    const float* __restrict__ fcW,  // may be null; [80][512]
    const float* __restrict__ fcb,  // [80]
    float* __restrict__ y_out)      // y[b*20480 + d] (for staged h_in)
{
  __shared__ float sh[16][516];   // +4 pad: 2-way bank aliasing only (free)
  __shared__ float sx[16][84];
  int tid = threadIdx.x;
  int rt = blockIdx.x & 15, jt = blockIdx.x >> 4;
  int row0 = rt << 4;

  // stage h tile: 16 x 512 floats as float4
  for (int i = tid; i < 2048; i += 256) {
    int r = i >> 7, kq = i & 127;
    float4 v = *(const float4*)(h_in + (size_t)(row0 + r) * HDIM + (kq << 2));
    *(float4*)&sh[r][kq << 2] = v;
  }
  if (x) {
    for (int i = tid; i < 320; i += 256) {  // 16 rows x 20 float4
      int r = i / 20, dq = i % 20;
      float4 v = *(const float4*)(x + (size_t)(row0 + r) * ROWSTRIDE + (dq << 2));
      *(float4*)&sx[r][dq << 2] = v;
    }
  }
  __syncthreads();

  int r = tid & 15, j0 = tid >> 4;
  int j = (jt << 4) + j0;
  float a0 = bias[j], a1 = bias[512 + j], a2 = bias[1024 + j], a3 = bias[1536 + j];
  {
    const float4* w0 = (const float4*)(Whh + (size_t)j * HDIM);
    const float4* w1 = (const float4*)(Whh + (size_t)(512 + j) * HDIM);
    const float4* w2 = (const float4*)(Whh + (size_t)(1024 + j) * HDIM);
    const float4* w3 = (const float4*)(Whh + (size_t)(1536 + j) * HDIM);
    const float4* hv = (const float4*)&sh[r][0];
    #pragma unroll 4
    for (int kq = 0; kq < 128; kq++) {
      float4 h4 = hv[kq];
      float4 q0 = w0[kq], q1 = w1[kq], q2 = w2[kq], q3 = w3[kq];
      a0 += h4.x * q0.x + h4.y * q0.y + h4.z * q0.z + h4.w * q0.w;
      a1 += h4.x * q1.x + h4.y * q1.y + h4.z * q1.z + h4.w * q1.w;
      a2 += h4.x * q2.x + h4.y * q2.y + h4.z * q2.z + h4.w * q2.w;
      a3 += h4.x * q3.x + h4.y * q3.y + h4.z * q3.z + h4.w * q3.w;
    }
  }
  if (x) {
    const float4* u0 = (const float4*)(Wih + (size_t)j * DDIM);
    const float4* u1 = (const float4*)(Wih + (size_t)(512 + j) * DDIM);
    const float4* u2 = (const float4*)(Wih + (size_t)(1024 + j) * DDIM);
    const float4* u3 = (const float4*)(Wih + (size_t)(1536 + j) * DDIM);
    const float4* xv = (const float4*)&sx[r][0];
    #pragma unroll 4
    for (int dq = 0; dq < 20; dq++) {
      float4 x4 = xv[dq];
      float4 q0 = u0[dq], q1 = u1[dq], q2 = u2[dq], q3 = u3[dq];
      a0 += x4.x * q0.x + x4.y * q0.y + x4.z * q0.z + x4.w * q0.w;
      a1 += x4.x * q1.x + x4.y * q1.y + x4.z * q1.z + x4.w * q1.w;
      a2 += x4.x * q2.x + x4.y * q2.y + x4.z * q2.z + x4.w * q2.w;
      a3 += x4.x * q3.x + x4.y * q3.y + x4.z * q3.z + x4.w * q3.w;
    }
  }
  // fused elementwise: c' = sig(f)*c + sig(i)*tanh(g); h' = sig(o)*tanh(c')
  {
    size_t idx = (size_t)(row0 + r) * HDIM + j;
    float cv = c[idx];
    float ig = sigmoidf_(a0), fg = sigmoidf_(a1), gg = tanhf(a2), og = sigmoidf_(a3);
    float cn = fg * cv + ig * gg;
    float hn = og * tanhf(cn);
    c[idx] = cn;
    h_out[idx] = hn;
  }
  // fused y_{t-1} = h_in @ fc_W^T + fc_b  (3 output dims per j-block, 32 blocks cover 80)
  if (fcW) {
    int dloc = tid >> 4;
    if (dloc < 3) {
      int d = jt * 3 + dloc;
      if (d < DDIM) {
        const float4* fw = (const float4*)(fcW + (size_t)d * HDIM);
        const float4* hv2 = (const float4*)&sh[r][0];
        float acc = 0.f;
        #pragma unroll 4
        for (int kq = 0; kq < 128; kq++) {
          float4 h4 = hv2[kq];
          float4 f4 = fw[kq];
          acc += h4.x * f4.x + h4.y * f4.y + h4.z * f4.z + h4.w * f4.w;
        }
        y_out[(size_t)(row0 + r) * ROWSTRIDE + d] = acc + fcb[d];
      }
    }
  }
}

// ---------------- vector quantizer: argmin_k ||e_k||^2 - 2 z.e_k -----------------
__global__ __launch_bounds__(256) void vq_kernel(
    const float* __restrict__ z, const float* __restrict__ emb,
    float* __restrict__ quant, float* __restrict__ vq_part,
    float* __restrict__ out_idx) {
  __shared__ float sz[512];
  __shared__ float sd[256];
  __shared__ int si[256];
  int b = blockIdx.x, tid = threadIdx.x;
  sz[tid] = z[(size_t)b * HDIM + tid];
  sz[tid + 256] = z[(size_t)b * HDIM + 256 + tid];
  __syncthreads();
  float bd = 3.4e38f;
  int bk = 0;
  for (int k = tid; k < 512; k += 256) {
    const float4* e4 = (const float4*)(emb + (size_t)k * HDIM);
    const float4* z4 = (const float4*)sz;
    float dot = 0.f, ee = 0.f;
    #pragma unroll 4
    for (int q = 0; q < 128; q++) {
      float4 ev = e4[q], zv = z4[q];
      dot += ev.x * zv.x + ev.y * zv.y + ev.z * zv.z + ev.w * zv.w;
      ee += ev.x * ev.x + ev.y * ev.y + ev.z * ev.z + ev.w * ev.w;
    }
    float dist = ee - 2.f * dot;
    if (dist < bd) { bd = dist; bk = k; }  // k increasing: strict < keeps first min
  }
  sd[tid] = bd; si[tid] = bk;
  __syncthreads();
  for (int s = 128; s > 0; s >>= 1) {
    if (tid < s) {
      float od = sd[tid + s]; int ok = si[tid + s];
      if (od < sd[tid] || (od == sd[tid] && ok < si[tid])) { sd[tid] = od; si[tid] = ok; }
    }
    __syncthreads();
  }
  int kbest = si[0];
  __syncthreads();
  float e0 = emb[(size_t)kbest * HDIM + tid];
  float e1 = emb[(size_t)kbest * HDIM + 256 + tid];
  quant[(size_t)b * HDIM + tid] = e0;
  quant[(size_t)b * HDIM + 256 + tid] = e1;
  float q0 = e0 - sz[tid], q1 = e1 - sz[tid + 256];
  sd[tid] = q0 * q0 + q1 * q1;
  __syncthreads();
  for (int s = 128; s > 0; s >>= 1) {
    if (tid < s) sd[tid] += sd[tid + s];
    __syncthreads();
  }
  if (tid == 0) { vq_part[b] = sd[0]; out_idx[b] = (float)kbest; }
}

__global__ __launch_bounds__(256) void vq_reduce_kernel(const float* __restrict__ vq_part,
                                                        float* __restrict__ out_loss) {
  __shared__ float s[256];
  int tid = threadIdx.x;
  s[tid] = vq_part[tid];
  __syncthreads();
  for (int st = 128; st > 0; st >>= 1) {
    if (tid < st) s[tid] += s[tid + st];
    __syncthreads();
  }
  if (tid == 0) out_loss[0] = s[0] * 1.25f / (float)(BB * HDIM);  // (q + 0.25 e) latent
}

// ---------------- standalone y = h @ fc_W^T + fc_b -------------------------------
__global__ __launch_bounds__(128) void y_kernel(const float* __restrict__ h,
                                                const float* __restrict__ fcW,
                                                const float* __restrict__ fcb,
                                                float* __restrict__ y) {
  __shared__ float shh[512];
  int b = blockIdx.x, tid = threadIdx.x;
  for (int i = tid; i < 512; i += 128) shh[i] = h[(size_t)b * HDIM + i];
  __syncthreads();
  if (tid < DDIM) {
    const float4* fw = (const float4*)(fcW + (size_t)tid * HDIM);
    const float4* hv = (const float4*)shh;
    float acc = 0.f;
    #pragma unroll 4
    for (int q = 0; q < 128; q++) {
      float4 f4 = fw[q], h4 = hv[q];
      acc += f4.x * h4.x + f4.y * h4.y + f4.z * h4.z + f4.w * h4.w;
    }
    y[(size_t)b * ROWSTRIDE + tid] = acc + fcb[tid];
  }
}

extern "C" void kernel_launch(void* const* d_in, const int* in_sizes, int n_in,
                              void* d_out, int out_size, void* d_ws, size_t ws_size,
                              hipStream_t stream) {
  const float* traj = (const float*)d_in[0];
  // d_in[1] = seq_len (==256, hardcoded)
  const float* eWih = (const float*)d_in[2];
  const float* eWhh = (const float*)d_in[3];
  const float* eb1  = (const float*)d_in[4];
  const float* eb2  = (const float*)d_in[5];
  const float* emb  = (const float*)d_in[6];
  const float* dWih = (const float*)d_in[7];
  const float* dWhh = (const float*)d_in[8];
  const float* db1  = (const float*)d_in[9];
  const float* db2  = (const float*)d_in[10];
  const float* fcW  = (const float*)d_in[11];
  const float* fcb  = (const float*)d_in[12];

  float* out = (float*)d_out;
  float* recon = out;                       // [256][256][80]
  float* out_loss = out + 5242880;          // scalar
  float* out_idx = out + 5242881;           // [256] written as float

  float* ws = (float*)d_ws;
  float* hA = ws;                 // 131072 (zeroed; also holds final z)
  float* cE = ws + 131072;        // (zeroed)
  float* cD = ws + 262144;        // (zeroed)
  float* hB = ws + 393216;
  float* dh0 = ws + 524288;
  float* dh1 = ws + 655360;
  float* quant = ws + 786432;
  float* vq_part = ws + 917504;   // 256
  float* b_enc = ws + 917760;     // 2048
  float* b_dec0 = ws + 919808;    // 2048
  float* b_eff = ws + 921856;     // 2048
  float* W_eff = ws + 923904;     // 1048576 -> total 1972480 floats (~7.9 MB)
  const int use_fold = (ws_size >= (size_t)1972480 * sizeof(float)) ? 1 : 0;

  // init h0/c0 (harness poisons ws with 0xAA)
  zero_kernel<<<384, 256, 0, stream>>>((float4*)ws, 98304);
  bias_init_kernel<<<8, 256, 0, stream>>>(eb1, eb2, db1, db2, dWih, fcb,
                                          b_enc, b_dec0, b_eff, use_fold);
  if (use_fold) fold_kernel<<<2048, 256, 0, stream>>>(dWih, dWhh, fcW, W_eff);

  // ---- encoder: 256 steps, h ping-pong hA<->hB, final z lands in hA ----
  const float* hin = hA;
  for (int t = 0; t < TT; t++) {
    float* hout = (t & 1) ? hA : hB;
    lstm_step_kernel<<<512, 256, 0, stream>>>(traj + t * DDIM, eWih, eWhh, b_enc,
                                              hin, cE, hout, nullptr, nullptr, nullptr);
    hin = hout;
  }

  // ---- VQ ----
  vq_kernel<<<256, 256, 0, stream>>>(hA, emb, quant, vq_part, out_idx);
  vq_reduce_kernel<<<1, 256, 0, stream>>>(vq_part, out_loss);

  // ---- decoder: 256 steps ----
  hin = quant;
  if (use_fold) {
    // x folded into W_eff; y_{t-1} fused into step t; final y separately
    for (int t = 0; t < TT; t++) {
      float* hout = (t & 1) ? dh1 : dh0;
      lstm_step_kernel<<<512, 256, 0, stream>>>(
          nullptr, nullptr,
          (t == 0) ? dWhh : W_eff, (t == 0) ? b_dec0 : b_eff,
          hin, cD, hout,
          (t == 0) ? nullptr : fcW, fcb,
          (t == 0) ? nullptr : (recon + (t - 1) * DDIM));
      hin = hout;
    }
    y_kernel<<<256, 128, 0, stream>>>(dh1, fcW, fcb, recon + 255 * DDIM);
  } else {
    // fallback: x read back from recon (written by previous step's y_kernel)
    for (int t = 0; t < TT; t++) {
      float* hout = (t & 1) ? dh1 : dh0;
      lstm_step_kernel<<<512, 256, 0, stream>>>(
          (t == 0) ? nullptr : (recon + (t - 1) * DDIM), dWih,
          dWhh, b_dec0, hin, cD, hout, nullptr, nullptr, nullptr);
      y_kernel<<<256, 128, 0, stream>>>(hout, fcW, fcb, recon + t * DDIM);
      hin = hout;
    }
  }
}